// Round 12
// baseline (224.641 us; speedup 1.0000x reference)
//
#include <hip/hip_runtime.h>
#include <hip/hip_bf16.h>

#define T_TOK 2048
#define HDIM  2048
#define FDIM  1024
#define NEXP  8
#define KSEL  2
#define NENT  (T_TOK*KSEL)   // 4096 routing entries
#define WMAX  40             // max 128-row work items (32 + 7 tail + margin)

typedef __attribute__((ext_vector_type(8))) short   short8v;
typedef __attribute__((ext_vector_type(4))) float   floatx4;
typedef __attribute__((ext_vector_type(4))) unsigned short ushort4v;

__device__ __forceinline__ unsigned short f2bf(float f) {
  unsigned int u = __builtin_bit_cast(unsigned int, f);
  u += 0x7FFFu + ((u >> 16) & 1u);
  return (unsigned short)(u >> 16);
}

__device__ __forceinline__ short8v cvt8(floatx4 v0, floatx4 v1, float sc) {
  short8v r = { (short)f2bf(v0.x*sc), (short)f2bf(v0.y*sc),
                (short)f2bf(v0.z*sc), (short)f2bf(v0.w*sc),
                (short)f2bf(v1.x*sc), (short)f2bf(v1.y*sc),
                (short)f2bf(v1.z*sc), (short)f2bf(v1.w*sc) };
  return r;
}

__device__ __forceinline__ void gll16(const void* g, void* l) {
  __builtin_amdgcn_global_load_lds(
      (const __attribute__((address_space(1))) unsigned int*)g,
      (__attribute__((address_space(3))) unsigned int*)l, 16, 0, 0);
}

// ---- workspace layout ----
// wsI[0:8) cnt | wsI[8:16) cursor | wsI[16:24) offsets | wsI[24] nWork
// wsI[48:88) work list (e<<8 | block128)
// wsI[128:128+4096) entry token | (float*)[4096] entry weight
// byte 65536: hb (8 MiB) | wgb (64 MiB) | wdb (32 MiB) | act (8 MiB)
#define ETOK_OFF 128

__global__ void k_count(const int* __restrict__ ids, int* __restrict__ wsI) {
  int g = blockIdx.x * 256 + threadIdx.x;
  if (g < NENT) atomicAdd(&wsI[ids[g] & 7], 1);
}

__global__ void k_scan(int* __restrict__ wsI) {
  int s = 0, nW = 0;
  int* wl = wsI + 48;
  for (int e = 0; e < NEXP; e++) {
    wsI[16 + e] = s;
    int c = wsI[e];
    s += c;
    int nb = (c + 127) >> 7;
    for (int rb = 0; rb < nb; rb++) wl[nW++] = (e << 8) | rb;
  }
  wsI[24] = nW;
}

__global__ void k_scatter(const int* __restrict__ ids, const float* __restrict__ tw,
                          int* __restrict__ wsI) {
  int g = blockIdx.x * 256 + threadIdx.x;
  if (g >= NENT) return;
  int e = ids[g] & 7;
  int pos = atomicAdd(&wsI[8 + e], 1);
  int idx = wsI[16 + e] + pos;
  int*   etok = wsI + ETOK_OFF;
  float* ew   = (float*)(wsI + ETOK_OFF + NENT);
  etok[idx] = g >> 1;
  ew[idx]   = tw[g];
}

// fast zero of d_out (the runtime's fill kernel measured 218 GB/s / 75 us)
__global__ __launch_bounds__(256) void k_zero(float* __restrict__ p) {
  const int N = T_TOK * HDIM / 4;   // 1048576 float4
  for (int c = blockIdx.x * 256 + threadIdx.x; c < N; c += 2048 * 256) {
    floatx4 z = {0.f, 0.f, 0.f, 0.f};
    *(floatx4*)(p + (size_t)c * 4) = z;
  }
}

// ---- prep: bf16 casts / dequant (streaming, BW-bound) ----
__global__ __launch_bounds__(256) void k_cast_h(const float* __restrict__ h,
                                                unsigned short* __restrict__ o) {
  const int N = T_TOK * HDIM / 8;   // 524288
  int c = blockIdx.x * 256 + threadIdx.x;
  if (c >= N) return;
  const floatx4 v0 = *(const floatx4*)(h + (size_t)c * 8);
  const floatx4 v1 = *(const floatx4*)(h + (size_t)c * 8 + 4);
  *(short8v*)(o + (size_t)c * 8) = cvt8(v0, v1, 1.f);
}

__global__ __launch_bounds__(256) void k_dq_gu(const float* __restrict__ w,
                                               const float* __restrict__ s,
                                               unsigned short* __restrict__ o) {
  const int N = NEXP * 2 * FDIM * HDIM / 8;   // 4194304
  for (int c = blockIdx.x * 256 + threadIdx.x; c < N; c += 8192 * 256) {
    int h8  = c & 255;
    int row = c >> 8;
    int e   = row >> 11;
    int orow = row & 2047;
    float sc = s[e * 256 + (orow >> 7) * 16 + (h8 >> 4)];
    const floatx4 v0 = *(const floatx4*)(w + (size_t)c * 8);
    const floatx4 v1 = *(const floatx4*)(w + (size_t)c * 8 + 4);
    *(short8v*)(o + (size_t)c * 8) = cvt8(v0, v1, sc);
  }
}

__global__ __launch_bounds__(256) void k_dq_dn(const float* __restrict__ w,
                                               const float* __restrict__ s,
                                               unsigned short* __restrict__ o) {
  const int N = NEXP * HDIM * FDIM / 8;       // 2097152
  for (int c = blockIdx.x * 256 + threadIdx.x; c < N; c += 8192 * 256) {
    int f8  = c & 127;
    int row = c >> 7;
    int e   = row >> 11;
    int h   = row & 2047;
    float sc = s[e * 128 + (h >> 7) * 8 + (f8 >> 4)];
    const floatx4 v0 = *(const floatx4*)(w + (size_t)c * 8);
    const floatx4 v1 = *(const floatx4*)(w + (size_t)c * 8 + 4);
    *(short8v*)(o + (size_t)c * 8) = cvt8(v0, v1, sc);
  }
}

// ---- GEMM1: act = silu(h@Wg^T)*(h@Wu^T); BM=128 x 32 act-cols; bf16 gll16 ----
// grid (WMAX, 32): B-tile = 32 gate + 32 up rows, BK=64, 2-barrier loop.
__global__ __launch_bounds__(256, 5) void k_gemm1n(
    const unsigned short* __restrict__ hb,
    const unsigned short* __restrict__ wgb,
    const int* __restrict__ wsI,
    unsigned short* __restrict__ act)
{
  if ((int)blockIdx.x >= wsI[24]) return;
  const int item = wsI[48 + blockIdx.x];
  const int e    = item >> 8;
  const int r0   = (item & 255) << 7;
  const int cnt  = wsI[e];
  const int off  = wsI[16 + e];
  const int c0   = blockIdx.y * 32;          // act col base
  const int* etok = wsI + ETOK_OFF;

  __shared__ unsigned short As[128][64];     // 16 KB
  __shared__ unsigned short Bs[64][64];      // 8 KB

  const int tid = threadIdx.x, lane = tid & 63, w = tid >> 6;
  const int kg = lane >> 4, l15 = lane & 15, lr = lane >> 3, lc = lane & 7;
  const int wr = (w >> 1) * 64, wc = w & 1;

  unsigned int aoff[4];
#pragma unroll
  for (int i = 0; i < 4; i++) {
    int ra  = (w * 4 + i) * 8 + lr;
    int swz = (lc ^ (ra & 7)) * 8;
    int ent = r0 + ra; if (ent >= cnt) ent = cnt - 1;
    aoff[i] = (unsigned)etok[off + ent] * 2048u + (unsigned)swz;
  }
  unsigned int boff[2];
#pragma unroll
  for (int i = 0; i < 2; i++) {
    int rb  = (w * 2 + i) * 8 + lr;          // [0,64)
    int swz = (lc ^ (rb & 7)) * 8;
    int gr  = (rb < 32) ? (c0 + rb) : (1024 + c0 + rb - 32);
    boff[i] = ((unsigned)e * 2048u + (unsigned)gr) * 2048u + (unsigned)swz;
  }

  floatx4 acc[4][2] = {};

  for (int k0 = 0; k0 < HDIM; k0 += 64) {
#pragma unroll
    for (int i = 0; i < 4; i++)
      gll16(hb + aoff[i] + k0, (char*)As + (w * 4 + i) * 1024);
#pragma unroll
    for (int i = 0; i < 2; i++)
      gll16(wgb + boff[i] + k0, (char*)Bs + (w * 2 + i) * 1024);
    __syncthreads();

    const char* Ab = (const char*)As;
    const char* Bb = (const char*)Bs;
#pragma unroll
    for (int ks = 0; ks < 2; ks++) {
      short8v a[4], b[2];
#pragma unroll
      for (int m = 0; m < 4; m++) {
        int r = wr + m * 16 + l15;
        a[m] = *(const short8v*)(Ab + r * 128 + (((ks * 4 + kg) ^ (r & 7)) << 4));
      }
#pragma unroll
      for (int n = 0; n < 2; n++) {
        int rb = n * 32 + wc * 16 + l15;
        b[n] = *(const short8v*)(Bb + rb * 128 + (((ks * 4 + kg) ^ (rb & 7)) << 4));
      }
#pragma unroll
      for (int m = 0; m < 4; m++)
#pragma unroll
        for (int n = 0; n < 2; n++)
          acc[m][n] = __builtin_amdgcn_mfma_f32_16x16x32_bf16(a[m], b[n], acc[m][n], 0, 0, 0);
    }
    __syncthreads();
  }

#pragma unroll
  for (int m = 0; m < 4; m++) {
    int rbase = r0 + wr + m * 16 + kg * 4;
#pragma unroll
    for (int reg = 0; reg < 4; reg++) {
      int rr = rbase + reg;
      if (rr < cnt) {
        float g = acc[m][0][reg];
        float u = acc[m][1][reg];
        float a = g / (1.f + __expf(-g)) * u;
        act[(size_t)(off + rr) * FDIM + c0 + wc * 16 + l15] = f2bf(a);
      }
    }
  }
}

// ---- GEMM2: out[tok] += w_entry * (act @ Wdn^T); BM=128 x 64 h-cols ----
// grid (WMAX, 32): B-tile = 64 rows, BK=64, 2-barrier loop, atomic epilogue.
__global__ __launch_bounds__(256, 5) void k_gemm2n(
    const unsigned short* __restrict__ wdb,
    const int* __restrict__ wsI,
    const unsigned short* __restrict__ act,
    float* __restrict__ out)
{
  if ((int)blockIdx.x >= wsI[24]) return;
  const int item = wsI[48 + blockIdx.x];
  const int e    = item >> 8;
  const int r0   = (item & 255) << 7;
  const int cnt  = wsI[e];
  const int off  = wsI[16 + e];
  const int c0   = blockIdx.y * 64;          // h col base
  const int* etok = wsI + ETOK_OFF;
  const float* ew = (const float*)(wsI + ETOK_OFF + NENT);

  __shared__ unsigned short As[128][64];     // 16 KB
  __shared__ unsigned short Bs[64][64];      // 8 KB

  const int tid = threadIdx.x, lane = tid & 63, w = tid >> 6;
  const int kg = lane >> 4, l15 = lane & 15, lr = lane >> 3, lc = lane & 7;
  const int wr = (w >> 1) * 64, wc = w & 1;

  unsigned int aoff[4];
#pragma unroll
  for (int i = 0; i < 4; i++) {
    int ra  = (w * 4 + i) * 8 + lr;
    int swz = (lc ^ (ra & 7)) * 8;
    int ent = r0 + ra; if (ent >= cnt) ent = cnt - 1;
    aoff[i] = (unsigned)(off + ent) * 1024u + (unsigned)swz;
  }
  unsigned int boff[2];
#pragma unroll
  for (int i = 0; i < 2; i++) {
    int rb  = (w * 2 + i) * 8 + lr;
    int swz = (lc ^ (rb & 7)) * 8;
    boff[i] = ((unsigned)e * 2048u + (unsigned)(c0 + rb)) * 1024u + (unsigned)swz;
  }

  floatx4 acc[4][2] = {};

  for (int k0 = 0; k0 < FDIM; k0 += 64) {
#pragma unroll
    for (int i = 0; i < 4; i++)
      gll16(act + aoff[i] + k0, (char*)As + (w * 4 + i) * 1024);
#pragma unroll
    for (int i = 0; i < 2; i++)
      gll16(wdb + boff[i] + k0, (char*)Bs + (w * 2 + i) * 1024);
    __syncthreads();

    const char* Ab = (const char*)As;
    const char* Bb = (const char*)Bs;
#pragma unroll
    for (int ks = 0; ks < 2; ks++) {
      short8v a[4], b[2];
#pragma unroll
      for (int m = 0; m < 4; m++) {
        int r = wr + m * 16 + l15;
        a[m] = *(const short8v*)(Ab + r * 128 + (((ks * 4 + kg) ^ (r & 7)) << 4));
      }
#pragma unroll
      for (int n = 0; n < 2; n++) {
        int rb = wc * 32 + n * 16 + l15;
        b[n] = *(const short8v*)(Bb + rb * 128 + (((ks * 4 + kg) ^ (rb & 7)) << 4));
      }
#pragma unroll
      for (int m = 0; m < 4; m++)
#pragma unroll
        for (int n = 0; n < 2; n++)
          acc[m][n] = __builtin_amdgcn_mfma_f32_16x16x32_bf16(a[m], b[n], acc[m][n], 0, 0, 0);
    }
    __syncthreads();
  }

#pragma unroll
  for (int m = 0; m < 4; m++) {
    int rbase = r0 + wr + m * 16 + kg * 4;
#pragma unroll
    for (int reg = 0; reg < 4; reg++) {
      int rr = rbase + reg;
      if (rr < cnt) {
        int tok   = etok[off + rr];
        float wgt = ew[off + rr];
#pragma unroll
        for (int n = 0; n < 2; n++)
          atomicAdd(&out[(size_t)tok * HDIM + c0 + wc * 32 + n * 16 + l15],
                    wgt * acc[m][n][reg]);
      }
    }
  }
}

// ================= fallback (round-1 passing kernels) =================
__global__ __launch_bounds__(256) void k_gemm1_fb(
    const float* __restrict__ hidden, const float* __restrict__ wgu,
    const float* __restrict__ sgu, const int* __restrict__ wsI,
    unsigned short* __restrict__ act)
{
  const int e = blockIdx.y; const int cnt = wsI[e];
  const int r0 = blockIdx.x * 128; if (r0 >= cnt) return;
  const int off = wsI[16 + e]; const int c0 = blockIdx.z * 64;
  const int* etok = wsI + ETOK_OFF;
  __shared__ unsigned short As[128][40]; __shared__ unsigned short Bs[128][40];
  const int tid = threadIdx.x, lane = tid & 63, wv = tid >> 6;
  const int wr = (wv >> 1) * 64, wc = wv & 1, kg = lane >> 4, l15 = lane & 15;
  floatx4 acc[4][4] = {};
  for (int k0 = 0; k0 < HDIM; k0 += 32) {
#pragma unroll
    for (int c = tid; c < 1024; c += 256) {
      int row = c >> 3, k4 = c & 7;
      int rg = r0 + row; if (rg >= cnt) rg = cnt - 1;
      int tok = etok[off + rg];
      const floatx4 v = *(const floatx4*)&hidden[(size_t)tok * HDIM + k0 + k4 * 4];
      ushort4v o = { f2bf(v.x), f2bf(v.y), f2bf(v.z), f2bf(v.w) };
      *(ushort4v*)&As[row][k4 * 4] = o;
    }
#pragma unroll
    for (int c = tid; c < 1024; c += 256) {
      int row = c >> 3, k4 = c & 7;
      int gr = (row < 64) ? (c0 + row) : (FDIM + c0 + row - 64);
      float s = sgu[e * 256 + (gr >> 7) * 16 + (k0 >> 7)];
      const floatx4 v = *(const floatx4*)&wgu[((size_t)e * 2048 + gr) * HDIM + k0 + k4 * 4];
      ushort4v o = { f2bf(v.x * s), f2bf(v.y * s), f2bf(v.z * s), f2bf(v.w * s) };
      *(ushort4v*)&Bs[row][k4 * 4] = o;
    }
    __syncthreads();
    short8v a[4], b[4];
#pragma unroll
    for (int m = 0; m < 4; m++) a[m] = *(const short8v*)&As[wr + m * 16 + l15][kg * 8];
#pragma unroll
    for (int n = 0; n < 4; n++) {
      int br = (n < 2) ? (wc * 32 + n * 16) : (64 + wc * 32 + (n - 2) * 16);
      b[n] = *(const short8v*)&Bs[br + l15][kg * 8];
    }
#pragma unroll
    for (int m = 0; m < 4; m++)
#pragma unroll
      for (int n = 0; n < 4; n++)
        acc[m][n] = __builtin_amdgcn_mfma_f32_16x16x32_bf16(a[m], b[n], acc[m][n], 0, 0, 0);
    __syncthreads();
  }
#pragma unroll
  for (int m = 0; m < 4; m++) {
    int rbase = r0 + wr + m * 16 + kg * 4;
#pragma unroll
    for (int reg = 0; reg < 4; reg++) {
      int rr = rbase + reg;
      if (rr < cnt) {
#pragma unroll
        for (int n = 0; n < 2; n++) {
          float g = acc[m][n][reg], u = acc[m][n + 2][reg];
          float a = g / (1.f + expf(-g)) * u;
          act[(size_t)(off + rr) * FDIM + c0 + wc * 32 + n * 16 + l15] = f2bf(a);
        }
      }
    }
  }
}

__global__ __launch_bounds__(256) void k_gemm2_fb(
    const float* __restrict__ wdn, const float* __restrict__ sdn,
    const int* __restrict__ wsI, const unsigned short* __restrict__ act,
    float* __restrict__ out)
{
  const int e = blockIdx.y; const int cnt = wsI[e];
  const int r0 = blockIdx.x * 128; if (r0 >= cnt) return;
  const int off = wsI[16 + e]; const int c0 = blockIdx.z * 128;
  const int* etok = wsI + ETOK_OFF;
  const float* ew = (const float*)(wsI + ETOK_OFF + NENT);
  __shared__ unsigned short As[128][40]; __shared__ unsigned short Bs[128][40];
  const int tid = threadIdx.x, lane = tid & 63, wv = tid >> 6;
  const int wr = (wv >> 1) * 64, wc = wv & 1, kg = lane >> 4, l15 = lane & 15;
  floatx4 acc[4][4] = {};
  for (int k0 = 0; k0 < FDIM; k0 += 32) {
#pragma unroll
    for (int c = tid; c < 512; c += 256) {
      int row = c >> 2, k8 = c & 3;
      int rg = r0 + row; if (rg >= cnt) rg = cnt - 1;
      short8v v = *(const short8v*)&act[(size_t)(off + rg) * FDIM + k0 + k8 * 8];
      *(short8v*)&As[row][k8 * 8] = v;
    }
#pragma unroll
    for (int c = tid; c < 1024; c += 256) {
      int row = c >> 3, k4 = c & 7;
      int gr = c0 + row;
      float s = sdn[e * 128 + (gr >> 7) * 8 + (k0 >> 7)];
      const floatx4 v = *(const floatx4*)&wdn[((size_t)e * HDIM + gr) * FDIM + k0 + k4 * 4];
      ushort4v o = { f2bf(v.x * s), f2bf(v.y * s), f2bf(v.z * s), f2bf(v.w * s) };
      *(ushort4v*)&Bs[row][k4 * 4] = o;
    }
    __syncthreads();
    short8v a[4], b[4];
#pragma unroll
    for (int m = 0; m < 4; m++) a[m] = *(const short8v*)&As[wr + m * 16 + l15][kg * 8];
#pragma unroll
    for (int n = 0; n < 4; n++) b[n] = *(const short8v*)&Bs[wc * 64 + n * 16 + l15][kg * 8];
#pragma unroll
    for (int m = 0; m < 4; m++)
#pragma unroll
      for (int n = 0; n < 4; n++)
        acc[m][n] = __builtin_amdgcn_mfma_f32_16x16x32_bf16(a[m], b[n], acc[m][n], 0, 0, 0);
    __syncthreads();
  }
#pragma unroll
  for (int m = 0; m < 4; m++) {
    int rbase = r0 + wr + m * 16 + kg * 4;
#pragma unroll
    for (int reg = 0; reg < 4; reg++) {
      int rr = rbase + reg;
      if (rr < cnt) {
        int tok = etok[off + rr];
        float ww = ew[off + rr];
#pragma unroll
        for (int n = 0; n < 4; n++)
          atomicAdd(&out[(size_t)tok * HDIM + c0 + wc * 64 + n * 16 + l15], ww * acc[m][n][reg]);
      }
    }
  }
}

extern "C" void kernel_launch(void* const* d_in, const int* in_sizes, int n_in,
                              void* d_out, int out_size, void* d_ws, size_t ws_size,
                              hipStream_t stream) {
  const float* hidden = (const float*)d_in[0];
  const float* tw     = (const float*)d_in[1];
  const int*   ids    = (const int*)d_in[2];
  const float* wgu    = (const float*)d_in[3];
  const float* sgu    = (const float*)d_in[4];
  const float* wdn    = (const float*)d_in[5];
  const float* sdn    = (const float*)d_in[6];
  float* out = (float*)d_out;
  int* wsI = (int*)d_ws;

  hipMemsetAsync(d_ws, 0, 512, stream);
  k_zero   <<<2048, 256, 0, stream>>>(out);
  k_count  <<<16, 256, 0, stream>>>(ids, wsI);
  k_scan   <<<1, 1, 0, stream>>>(wsI);
  k_scatter<<<16, 256, 0, stream>>>(ids, tw, wsI);

  const size_t NEED = 65536ull + (113ull << 20);
  if (ws_size >= NEED) {
    unsigned short* hb  = (unsigned short*)((char*)d_ws + 65536);
    unsigned short* wgb = hb  + (size_t)T_TOK * HDIM;
    unsigned short* wdb = wgb + (size_t)NEXP * 2 * FDIM * HDIM;
    unsigned short* act = wdb + (size_t)NEXP * HDIM * FDIM;

    k_cast_h<<<T_TOK * HDIM / 8 / 256, 256, 0, stream>>>(hidden, hb);
    k_dq_gu <<<8192, 256, 0, stream>>>(wgu, sgu, wgb);
    k_dq_dn <<<8192, 256, 0, stream>>>(wdn, sdn, wdb);

    dim3 g1(WMAX, 32);
    k_gemm1n<<<g1, 256, 0, stream>>>(hb, wgb, wsI, act);
    dim3 g2(WMAX, 32);
    k_gemm2n<<<g2, 256, 0, stream>>>(wdb, wsI, act, out);
  } else {
    unsigned short* act = (unsigned short*)((char*)d_ws + 65536);
    dim3 g1(NENT / 128, NEXP, FDIM / 64);
    k_gemm1_fb<<<g1, 256, 0, stream>>>(hidden, wgu, sgu, wsI, act);
    dim3 g2(NENT / 128, NEXP, HDIM / 128);
    k_gemm2_fb<<<g2, 256, 0, stream>>>(wdn, sdn, wsI, act, out);
  }
}

// Round 13
// 221.738 us; speedup vs baseline: 1.0131x; 1.0131x over previous
//
#include <hip/hip_runtime.h>
#include <hip/hip_bf16.h>

#define T_TOK 2048
#define HDIM  2048
#define FDIM  1024
#define NEXP  8
#define KSEL  2
#define NENT  (T_TOK*KSEL)   // 4096 routing entries
#define WMAX  40             // max 128-row work items (32 + 7 tail + margin)

typedef __attribute__((ext_vector_type(8))) short   short8v;
typedef __attribute__((ext_vector_type(4))) float   floatx4;
typedef __attribute__((ext_vector_type(4))) unsigned short ushort4v;

__device__ __forceinline__ unsigned short f2bf(float f) {
  unsigned int u = __builtin_bit_cast(unsigned int, f);
  u += 0x7FFFu + ((u >> 16) & 1u);
  return (unsigned short)(u >> 16);
}

__device__ __forceinline__ short8v cvt8(floatx4 v0, floatx4 v1, float sc) {
  short8v r = { (short)f2bf(v0.x*sc), (short)f2bf(v0.y*sc),
                (short)f2bf(v0.z*sc), (short)f2bf(v0.w*sc),
                (short)f2bf(v1.x*sc), (short)f2bf(v1.y*sc),
                (short)f2bf(v1.z*sc), (short)f2bf(v1.w*sc) };
  return r;
}

__device__ __forceinline__ void gll16(const void* g, void* l) {
  __builtin_amdgcn_global_load_lds(
      (const __attribute__((address_space(1))) unsigned int*)g,
      (__attribute__((address_space(3))) unsigned int*)l, 16, 0, 0);
}

// ---- workspace layout ----
// wsI[0:8) cnt | wsI[8:16) cursor | wsI[16:24) offsets | wsI[24] nWork
// wsI[48:88) work list (e<<8 | block128)
// wsI[128:128+4096) entry token | (float*)[4096] entry weight
// byte 65536: hb (8 MiB) | wgb (64 MiB) | wdb (32 MiB) | act (8 MiB)
#define ETOK_OFF 128

// zero d_out AND the wsI header (512 B). The rocclr fill kernel costs a
// constant ~75 us per dispatch regardless of size (measured r11/r12), so we
// never call hipMemsetAsync in the timed graph.
__global__ __launch_bounds__(256) void k_zero(float* __restrict__ p,
                                              int* __restrict__ wsI) {
  if (blockIdx.x == 0 && threadIdx.x < 128) wsI[threadIdx.x] = 0;
  const int N = T_TOK * HDIM / 4;   // 1048576 float4
  for (int c = blockIdx.x * 256 + threadIdx.x; c < N; c += 2048 * 256) {
    floatx4 z = {0.f, 0.f, 0.f, 0.f};
    *(floatx4*)(p + (size_t)c * 4) = z;
  }
}

__global__ void k_count(const int* __restrict__ ids, int* __restrict__ wsI) {
  int g = blockIdx.x * 256 + threadIdx.x;
  if (g < NENT) atomicAdd(&wsI[ids[g] & 7], 1);
}

__global__ void k_scan(int* __restrict__ wsI) {
  int s = 0, nW = 0;
  int* wl = wsI + 48;
  for (int e = 0; e < NEXP; e++) {
    wsI[16 + e] = s;
    int c = wsI[e];
    s += c;
    int nb = (c + 127) >> 7;
    for (int rb = 0; rb < nb; rb++) wl[nW++] = (e << 8) | rb;
  }
  wsI[24] = nW;
}

__global__ void k_scatter(const int* __restrict__ ids, const float* __restrict__ tw,
                          int* __restrict__ wsI) {
  int g = blockIdx.x * 256 + threadIdx.x;
  if (g >= NENT) return;
  int e = ids[g] & 7;
  int pos = atomicAdd(&wsI[8 + e], 1);
  int idx = wsI[16 + e] + pos;
  int*   etok = wsI + ETOK_OFF;
  float* ew   = (float*)(wsI + ETOK_OFF + NENT);
  etok[idx] = g >> 1;
  ew[idx]   = tw[g];
}

// ---- prep: bf16 casts / dequant (streaming, BW-bound) ----
__global__ __launch_bounds__(256) void k_cast_h(const float* __restrict__ h,
                                                unsigned short* __restrict__ o) {
  const int N = T_TOK * HDIM / 8;   // 524288
  int c = blockIdx.x * 256 + threadIdx.x;
  if (c >= N) return;
  const floatx4 v0 = *(const floatx4*)(h + (size_t)c * 8);
  const floatx4 v1 = *(const floatx4*)(h + (size_t)c * 8 + 4);
  *(short8v*)(o + (size_t)c * 8) = cvt8(v0, v1, 1.f);
}

__global__ __launch_bounds__(256) void k_dq_gu(const float* __restrict__ w,
                                               const float* __restrict__ s,
                                               unsigned short* __restrict__ o) {
  const int N = NEXP * 2 * FDIM * HDIM / 8;   // 4194304
  for (int c = blockIdx.x * 256 + threadIdx.x; c < N; c += 8192 * 256) {
    int h8  = c & 255;
    int row = c >> 8;
    int e   = row >> 11;
    int orow = row & 2047;
    float sc = s[e * 256 + (orow >> 7) * 16 + (h8 >> 4)];
    const floatx4 v0 = *(const floatx4*)(w + (size_t)c * 8);
    const floatx4 v1 = *(const floatx4*)(w + (size_t)c * 8 + 4);
    *(short8v*)(o + (size_t)c * 8) = cvt8(v0, v1, sc);
  }
}

__global__ __launch_bounds__(256) void k_dq_dn(const float* __restrict__ w,
                                               const float* __restrict__ s,
                                               unsigned short* __restrict__ o) {
  const int N = NEXP * HDIM * FDIM / 8;       // 2097152
  for (int c = blockIdx.x * 256 + threadIdx.x; c < N; c += 8192 * 256) {
    int f8  = c & 127;
    int row = c >> 7;
    int e   = row >> 11;
    int h   = row & 2047;
    float sc = s[e * 128 + (h >> 7) * 8 + (f8 >> 4)];
    const floatx4 v0 = *(const floatx4*)(w + (size_t)c * 8);
    const floatx4 v1 = *(const floatx4*)(w + (size_t)c * 8 + 4);
    *(short8v*)(o + (size_t)c * 8) = cvt8(v0, v1, sc);
  }
}

// ---- GEMM1: act = silu(h@Wg^T)*(h@Wu^T); BM=128 x 32 act-cols; bf16 gll16 ----
// grid (WMAX, 32): B-tile = 32 gate + 32 up rows, BK=64, 2-barrier loop.
__global__ __launch_bounds__(256, 5) void k_gemm1n(
    const unsigned short* __restrict__ hb,
    const unsigned short* __restrict__ wgb,
    const int* __restrict__ wsI,
    unsigned short* __restrict__ act)
{
  if ((int)blockIdx.x >= wsI[24]) return;
  const int item = wsI[48 + blockIdx.x];
  const int e    = item >> 8;
  const int r0   = (item & 255) << 7;
  const int cnt  = wsI[e];
  const int off  = wsI[16 + e];
  const int c0   = blockIdx.y * 32;          // act col base
  const int* etok = wsI + ETOK_OFF;

  __shared__ unsigned short As[128][64];     // 16 KB
  __shared__ unsigned short Bs[64][64];      // 8 KB

  const int tid = threadIdx.x, lane = tid & 63, w = tid >> 6;
  const int kg = lane >> 4, l15 = lane & 15, lr = lane >> 3, lc = lane & 7;
  const int wr = (w >> 1) * 64, wc = w & 1;

  unsigned int aoff[4];
#pragma unroll
  for (int i = 0; i < 4; i++) {
    int ra  = (w * 4 + i) * 8 + lr;
    int swz = (lc ^ (ra & 7)) * 8;
    int ent = r0 + ra; if (ent >= cnt) ent = cnt - 1;
    aoff[i] = (unsigned)etok[off + ent] * 2048u + (unsigned)swz;
  }
  unsigned int boff[2];
#pragma unroll
  for (int i = 0; i < 2; i++) {
    int rb  = (w * 2 + i) * 8 + lr;          // [0,64)
    int swz = (lc ^ (rb & 7)) * 8;
    int gr  = (rb < 32) ? (c0 + rb) : (1024 + c0 + rb - 32);
    boff[i] = ((unsigned)e * 2048u + (unsigned)gr) * 2048u + (unsigned)swz;
  }

  floatx4 acc[4][2] = {};

  for (int k0 = 0; k0 < HDIM; k0 += 64) {
#pragma unroll
    for (int i = 0; i < 4; i++)
      gll16(hb + aoff[i] + k0, (char*)As + (w * 4 + i) * 1024);
#pragma unroll
    for (int i = 0; i < 2; i++)
      gll16(wgb + boff[i] + k0, (char*)Bs + (w * 2 + i) * 1024);
    __syncthreads();

    const char* Ab = (const char*)As;
    const char* Bb = (const char*)Bs;
#pragma unroll
    for (int ks = 0; ks < 2; ks++) {
      short8v a[4], b[2];
#pragma unroll
      for (int m = 0; m < 4; m++) {
        int r = wr + m * 16 + l15;
        a[m] = *(const short8v*)(Ab + r * 128 + (((ks * 4 + kg) ^ (r & 7)) << 4));
      }
#pragma unroll
      for (int n = 0; n < 2; n++) {
        int rb = n * 32 + wc * 16 + l15;
        b[n] = *(const short8v*)(Bb + rb * 128 + (((ks * 4 + kg) ^ (rb & 7)) << 4));
      }
#pragma unroll
      for (int m = 0; m < 4; m++)
#pragma unroll
        for (int n = 0; n < 2; n++)
          acc[m][n] = __builtin_amdgcn_mfma_f32_16x16x32_bf16(a[m], b[n], acc[m][n], 0, 0, 0);
    }
    __syncthreads();
  }

#pragma unroll
  for (int m = 0; m < 4; m++) {
    int rbase = r0 + wr + m * 16 + kg * 4;
#pragma unroll
    for (int reg = 0; reg < 4; reg++) {
      int rr = rbase + reg;
      if (rr < cnt) {
        float g = acc[m][0][reg];
        float u = acc[m][1][reg];
        float a = g / (1.f + __expf(-g)) * u;
        act[(size_t)(off + rr) * FDIM + c0 + wc * 16 + l15] = f2bf(a);
      }
    }
  }
}

// ---- GEMM2: out[tok] += w_entry * (act @ Wdn^T); BM=128 x 64 h-cols ----
// grid (WMAX, 32): B-tile = 64 rows, BK=64, 2-barrier loop, atomic epilogue.
__global__ __launch_bounds__(256, 5) void k_gemm2n(
    const unsigned short* __restrict__ wdb,
    const int* __restrict__ wsI,
    const unsigned short* __restrict__ act,
    float* __restrict__ out)
{
  if ((int)blockIdx.x >= wsI[24]) return;
  const int item = wsI[48 + blockIdx.x];
  const int e    = item >> 8;
  const int r0   = (item & 255) << 7;
  const int cnt  = wsI[e];
  const int off  = wsI[16 + e];
  const int c0   = blockIdx.y * 64;          // h col base
  const int* etok = wsI + ETOK_OFF;
  const float* ew = (const float*)(wsI + ETOK_OFF + NENT);

  __shared__ unsigned short As[128][64];     // 16 KB
  __shared__ unsigned short Bs[64][64];      // 8 KB

  const int tid = threadIdx.x, lane = tid & 63, w = tid >> 6;
  const int kg = lane >> 4, l15 = lane & 15, lr = lane >> 3, lc = lane & 7;
  const int wr = (w >> 1) * 64, wc = w & 1;

  unsigned int aoff[4];
#pragma unroll
  for (int i = 0; i < 4; i++) {
    int ra  = (w * 4 + i) * 8 + lr;
    int swz = (lc ^ (ra & 7)) * 8;
    int ent = r0 + ra; if (ent >= cnt) ent = cnt - 1;
    aoff[i] = (unsigned)(off + ent) * 1024u + (unsigned)swz;
  }
  unsigned int boff[2];
#pragma unroll
  for (int i = 0; i < 2; i++) {
    int rb  = (w * 2 + i) * 8 + lr;
    int swz = (lc ^ (rb & 7)) * 8;
    boff[i] = ((unsigned)e * 2048u + (unsigned)(c0 + rb)) * 1024u + (unsigned)swz;
  }

  floatx4 acc[4][2] = {};

  for (int k0 = 0; k0 < FDIM; k0 += 64) {
#pragma unroll
    for (int i = 0; i < 4; i++)
      gll16(act + aoff[i] + k0, (char*)As + (w * 4 + i) * 1024);
#pragma unroll
    for (int i = 0; i < 2; i++)
      gll16(wdb + boff[i] + k0, (char*)Bs + (w * 2 + i) * 1024);
    __syncthreads();

    const char* Ab = (const char*)As;
    const char* Bb = (const char*)Bs;
#pragma unroll
    for (int ks = 0; ks < 2; ks++) {
      short8v a[4], b[2];
#pragma unroll
      for (int m = 0; m < 4; m++) {
        int r = wr + m * 16 + l15;
        a[m] = *(const short8v*)(Ab + r * 128 + (((ks * 4 + kg) ^ (r & 7)) << 4));
      }
#pragma unroll
      for (int n = 0; n < 2; n++) {
        int rb = wc * 32 + n * 16 + l15;
        b[n] = *(const short8v*)(Bb + rb * 128 + (((ks * 4 + kg) ^ (rb & 7)) << 4));
      }
#pragma unroll
      for (int m = 0; m < 4; m++)
#pragma unroll
        for (int n = 0; n < 2; n++)
          acc[m][n] = __builtin_amdgcn_mfma_f32_16x16x32_bf16(a[m], b[n], acc[m][n], 0, 0, 0);
    }
    __syncthreads();
  }

#pragma unroll
  for (int m = 0; m < 4; m++) {
    int rbase = r0 + wr + m * 16 + kg * 4;
#pragma unroll
    for (int reg = 0; reg < 4; reg++) {
      int rr = rbase + reg;
      if (rr < cnt) {
        int tok   = etok[off + rr];
        float wgt = ew[off + rr];
#pragma unroll
        for (int n = 0; n < 2; n++)
          atomicAdd(&out[(size_t)tok * HDIM + c0 + wc * 32 + n * 16 + l15],
                    wgt * acc[m][n][reg]);
      }
    }
  }
}

// ================= fallback (round-1 passing kernels) =================
__global__ __launch_bounds__(256) void k_gemm1_fb(
    const float* __restrict__ hidden, const float* __restrict__ wgu,
    const float* __restrict__ sgu, const int* __restrict__ wsI,
    unsigned short* __restrict__ act)
{
  const int e = blockIdx.y; const int cnt = wsI[e];
  const int r0 = blockIdx.x * 128; if (r0 >= cnt) return;
  const int off = wsI[16 + e]; const int c0 = blockIdx.z * 64;
  const int* etok = wsI + ETOK_OFF;
  __shared__ unsigned short As[128][40]; __shared__ unsigned short Bs[128][40];
  const int tid = threadIdx.x, lane = tid & 63, wv = tid >> 6;
  const int wr = (wv >> 1) * 64, wc = wv & 1, kg = lane >> 4, l15 = lane & 15;
  floatx4 acc[4][4] = {};
  for (int k0 = 0; k0 < HDIM; k0 += 32) {
#pragma unroll
    for (int c = tid; c < 1024; c += 256) {
      int row = c >> 3, k4 = c & 7;
      int rg = r0 + row; if (rg >= cnt) rg = cnt - 1;
      int tok = etok[off + rg];
      const floatx4 v = *(const floatx4*)&hidden[(size_t)tok * HDIM + k0 + k4 * 4];
      ushort4v o = { f2bf(v.x), f2bf(v.y), f2bf(v.z), f2bf(v.w) };
      *(ushort4v*)&As[row][k4 * 4] = o;
    }
#pragma unroll
    for (int c = tid; c < 1024; c += 256) {
      int row = c >> 3, k4 = c & 7;
      int gr = (row < 64) ? (c0 + row) : (FDIM + c0 + row - 64);
      float s = sgu[e * 256 + (gr >> 7) * 16 + (k0 >> 7)];
      const floatx4 v = *(const floatx4*)&wgu[((size_t)e * 2048 + gr) * HDIM + k0 + k4 * 4];
      ushort4v o = { f2bf(v.x * s), f2bf(v.y * s), f2bf(v.z * s), f2bf(v.w * s) };
      *(ushort4v*)&Bs[row][k4 * 4] = o;
    }
    __syncthreads();
    short8v a[4], b[4];
#pragma unroll
    for (int m = 0; m < 4; m++) a[m] = *(const short8v*)&As[wr + m * 16 + l15][kg * 8];
#pragma unroll
    for (int n = 0; n < 4; n++) {
      int br = (n < 2) ? (wc * 32 + n * 16) : (64 + wc * 32 + (n - 2) * 16);
      b[n] = *(const short8v*)&Bs[br + l15][kg * 8];
    }
#pragma unroll
    for (int m = 0; m < 4; m++)
#pragma unroll
      for (int n = 0; n < 4; n++)
        acc[m][n] = __builtin_amdgcn_mfma_f32_16x16x32_bf16(a[m], b[n], acc[m][n], 0, 0, 0);
    __syncthreads();
  }
#pragma unroll
  for (int m = 0; m < 4; m++) {
    int rbase = r0 + wr + m * 16 + kg * 4;
#pragma unroll
    for (int reg = 0; reg < 4; reg++) {
      int rr = rbase + reg;
      if (rr < cnt) {
#pragma unroll
        for (int n = 0; n < 2; n++) {
          float g = acc[m][n][reg], u = acc[m][n + 2][reg];
          float a = g / (1.f + expf(-g)) * u;
          act[(size_t)(off + rr) * FDIM + c0 + wc * 32 + n * 16 + l15] = f2bf(a);
        }
      }
    }
  }
}

__global__ __launch_bounds__(256) void k_gemm2_fb(
    const float* __restrict__ wdn, const float* __restrict__ sdn,
    const int* __restrict__ wsI, const unsigned short* __restrict__ act,
    float* __restrict__ out)
{
  const int e = blockIdx.y; const int cnt = wsI[e];
  const int r0 = blockIdx.x * 128; if (r0 >= cnt) return;
  const int off = wsI[16 + e]; const int c0 = blockIdx.z * 128;
  const int* etok = wsI + ETOK_OFF;
  const float* ew = (const float*)(wsI + ETOK_OFF + NENT);
  __shared__ unsigned short As[128][40]; __shared__ unsigned short Bs[128][40];
  const int tid = threadIdx.x, lane = tid & 63, wv = tid >> 6;
  const int wr = (wv >> 1) * 64, wc = wv & 1, kg = lane >> 4, l15 = lane & 15;
  floatx4 acc[4][4] = {};
  for (int k0 = 0; k0 < FDIM; k0 += 32) {
#pragma unroll
    for (int c = tid; c < 512; c += 256) {
      int row = c >> 2, k8 = c & 3;
      int rg = r0 + row; if (rg >= cnt) rg = cnt - 1;
      short8v v = *(const short8v*)&act[(size_t)(off + rg) * FDIM + k0 + k8 * 8];
      *(short8v*)&As[row][k8 * 8] = v;
    }
#pragma unroll
    for (int c = tid; c < 1024; c += 256) {
      int row = c >> 3, k4 = c & 7;
      int gr = c0 + row;
      float s = sdn[e * 128 + (gr >> 7) * 8 + (k0 >> 7)];
      const floatx4 v = *(const floatx4*)&wdn[((size_t)e * HDIM + gr) * FDIM + k0 + k4 * 4];
      ushort4v o = { f2bf(v.x * s), f2bf(v.y * s), f2bf(v.z * s), f2bf(v.w * s) };
      *(ushort4v*)&Bs[row][k4 * 4] = o;
    }
    __syncthreads();
    short8v a[4], b[4];
#pragma unroll
    for (int m = 0; m < 4; m++) a[m] = *(const short8v*)&As[wr + m * 16 + l15][kg * 8];
#pragma unroll
    for (int n = 0; n < 4; n++) b[n] = *(const short8v*)&Bs[wc * 64 + n * 16 + l15][kg * 8];
#pragma unroll
    for (int m = 0; m < 4; m++)
#pragma unroll
      for (int n = 0; n < 4; n++)
        acc[m][n] = __builtin_amdgcn_mfma_f32_16x16x32_bf16(a[m], b[n], acc[m][n], 0, 0, 0);
    __syncthreads();
  }
#pragma unroll
  for (int m = 0; m < 4; m++) {
    int rbase = r0 + wr + m * 16 + kg * 4;
#pragma unroll
    for (int reg = 0; reg < 4; reg++) {
      int rr = rbase + reg;
      if (rr < cnt) {
        int tok = etok[off + rr];
        float ww = ew[off + rr];
#pragma unroll
        for (int n = 0; n < 4; n++)
          atomicAdd(&out[(size_t)tok * HDIM + c0 + wc * 64 + n * 16 + l15], ww * acc[m][n][reg]);
      }
    }
  }
}

extern "C" void kernel_launch(void* const* d_in, const int* in_sizes, int n_in,
                              void* d_out, int out_size, void* d_ws, size_t ws_size,
                              hipStream_t stream) {
  const float* hidden = (const float*)d_in[0];
  const float* tw     = (const float*)d_in[1];
  const int*   ids    = (const int*)d_in[2];
  const float* wgu    = (const float*)d_in[3];
  const float* sgu    = (const float*)d_in[4];
  const float* wdn    = (const float*)d_in[5];
  const float* sdn    = (const float*)d_in[6];
  float* out = (float*)d_out;
  int* wsI = (int*)d_ws;

  // no hipMemsetAsync anywhere: the rocclr fill kernel costs ~75 us flat.
  k_zero   <<<2048, 256, 0, stream>>>(out, wsI);
  k_count  <<<16, 256, 0, stream>>>(ids, wsI);
  k_scan   <<<1, 1, 0, stream>>>(wsI);
  k_scatter<<<16, 256, 0, stream>>>(ids, tw, wsI);

  const size_t NEED = 65536ull + (113ull << 20);
  if (ws_size >= NEED) {
    unsigned short* hb  = (unsigned short*)((char*)d_ws + 65536);
    unsigned short* wgb = hb  + (size_t)T_TOK * HDIM;
    unsigned short* wdb = wgb + (size_t)NEXP * 2 * FDIM * HDIM;
    unsigned short* act = wdb + (size_t)NEXP * HDIM * FDIM;

    k_cast_h<<<T_TOK * HDIM / 8 / 256, 256, 0, stream>>>(hidden, hb);
    k_dq_gu <<<8192, 256, 0, stream>>>(wgu, sgu, wgb);
    k_dq_dn <<<8192, 256, 0, stream>>>(wdn, sdn, wdb);

    dim3 g1(WMAX, 32);
    k_gemm1n<<<g1, 256, 0, stream>>>(hb, wgb, wsI, act);
    dim3 g2(WMAX, 32);
    k_gemm2n<<<g2, 256, 0, stream>>>(wdb, wsI, act, out);
  } else {
    unsigned short* act = (unsigned short*)((char*)d_ws + 65536);
    dim3 g1(NENT / 128, NEXP, FDIM / 64);
    k_gemm1_fb<<<g1, 256, 0, stream>>>(hidden, wgu, sgu, wsI, act);
    dim3 g2(NENT / 128, NEXP, HDIM / 128);
    k_gemm2_fb<<<g2, 256, 0, stream>>>(wdn, sdn, wsI, act, out);
  }
}

// Round 14
// 209.812 us; speedup vs baseline: 1.0707x; 1.0568x over previous
//
#include <hip/hip_runtime.h>
#include <hip/hip_bf16.h>

#define T_TOK 2048
#define HDIM  2048
#define FDIM  1024
#define NEXP  8
#define KSEL  2
#define NENT  (T_TOK*KSEL)   // 4096 routing entries
#define WMAX1 24             // max 256-row work items (16 + tail)
#define WMAX2 40             // max 128-row work items

typedef __attribute__((ext_vector_type(8))) short   short8v;
typedef __attribute__((ext_vector_type(4))) float   floatx4;
typedef __attribute__((ext_vector_type(4))) unsigned short ushort4v;

__device__ __forceinline__ unsigned short f2bf(float f) {
  unsigned int u = __builtin_bit_cast(unsigned int, f);
  u += 0x7FFFu + ((u >> 16) & 1u);
  return (unsigned short)(u >> 16);
}

__device__ __forceinline__ short8v cvt8(floatx4 v0, floatx4 v1, float sc) {
  short8v r = { (short)f2bf(v0.x*sc), (short)f2bf(v0.y*sc),
                (short)f2bf(v0.z*sc), (short)f2bf(v0.w*sc),
                (short)f2bf(v1.x*sc), (short)f2bf(v1.y*sc),
                (short)f2bf(v1.z*sc), (short)f2bf(v1.w*sc) };
  return r;
}

__device__ __forceinline__ void gll16(const void* g, void* l) {
  __builtin_amdgcn_global_load_lds(
      (const __attribute__((address_space(1))) unsigned int*)g,
      (__attribute__((address_space(3))) unsigned int*)l, 16, 0, 0);
}

// ---- workspace layout ----
// wsI[0:8) cnt | wsI[8:16) cursor | wsI[16:24) offsets
// wsI[24] nWork128 | wsI[25] nWork256
// wsI[48:88) wl128 (e<<8|blk) | wsI[96:120) wl256
// wsI[128:+4096) entry token | (float*)[4096] entry weight | [4096] inv map
// byte 65536: hb (8Mi) | wgb (64Mi) | wdb (32Mi) | act (8Mi) | oe (32Mi)
#define ETOK_OFF 128

// wsI header zero only (fast path; k_reduce fully writes d_out)
__global__ void k_init(int* __restrict__ wsI) {
  if (threadIdx.x < 128) wsI[threadIdx.x] = 0;
}

// fallback path: zero out + header (never hipMemsetAsync: rocclr fill is slow)
__global__ __launch_bounds__(256) void k_zero(float* __restrict__ p,
                                              int* __restrict__ wsI) {
  if (blockIdx.x == 0 && threadIdx.x < 128) wsI[threadIdx.x] = 0;
  const int N = T_TOK * HDIM / 4;
  for (int c = blockIdx.x * 256 + threadIdx.x; c < N; c += 2048 * 256) {
    floatx4 z = {0.f, 0.f, 0.f, 0.f};
    *(floatx4*)(p + (size_t)c * 4) = z;
  }
}

__global__ void k_count(const int* __restrict__ ids, int* __restrict__ wsI) {
  int g = blockIdx.x * 256 + threadIdx.x;
  if (g < NENT) atomicAdd(&wsI[ids[g] & 7], 1);
}

__global__ void k_scan(int* __restrict__ wsI) {
  int s = 0, n1 = 0, n2 = 0;
  int* wl1 = wsI + 48;
  int* wl2 = wsI + 96;
  for (int e = 0; e < NEXP; e++) {
    wsI[16 + e] = s;
    int c = wsI[e];
    s += c;
    int nb1 = (c + 127) >> 7;
    for (int rb = 0; rb < nb1; rb++) wl1[n1++] = (e << 8) | rb;
    int nb2 = (c + 255) >> 8;
    for (int rb = 0; rb < nb2; rb++) wl2[n2++] = (e << 8) | rb;
  }
  wsI[24] = n1;
  wsI[25] = n2;
}

__global__ void k_scatter(const int* __restrict__ ids, const float* __restrict__ tw,
                          int* __restrict__ wsI) {
  int g = blockIdx.x * 256 + threadIdx.x;
  if (g >= NENT) return;
  int e = ids[g] & 7;
  int pos = atomicAdd(&wsI[8 + e], 1);
  int idx = wsI[16 + e] + pos;
  int*   etok = wsI + ETOK_OFF;
  float* ew   = (float*)(wsI + ETOK_OFF + NENT);
  int*   inv  = wsI + ETOK_OFF + 2 * NENT;
  etok[idx] = g >> 1;
  ew[idx]   = tw[g];
  inv[g]    = idx;
}

// ---- prep: bf16 casts / dequant (streaming, BW-bound) ----
__global__ __launch_bounds__(256) void k_cast_h(const float* __restrict__ h,
                                                unsigned short* __restrict__ o) {
  const int N = T_TOK * HDIM / 8;
  int c = blockIdx.x * 256 + threadIdx.x;
  if (c >= N) return;
  const floatx4 v0 = *(const floatx4*)(h + (size_t)c * 8);
  const floatx4 v1 = *(const floatx4*)(h + (size_t)c * 8 + 4);
  *(short8v*)(o + (size_t)c * 8) = cvt8(v0, v1, 1.f);
}

__global__ __launch_bounds__(256) void k_dq_gu(const float* __restrict__ w,
                                               const float* __restrict__ s,
                                               unsigned short* __restrict__ o) {
  const int N = NEXP * 2 * FDIM * HDIM / 8;
  for (int c = blockIdx.x * 256 + threadIdx.x; c < N; c += 8192 * 256) {
    int h8  = c & 255;
    int row = c >> 8;
    int e   = row >> 11;
    int orow = row & 2047;
    float sc = s[e * 256 + (orow >> 7) * 16 + (h8 >> 4)];
    const floatx4 v0 = *(const floatx4*)(w + (size_t)c * 8);
    const floatx4 v1 = *(const floatx4*)(w + (size_t)c * 8 + 4);
    *(short8v*)(o + (size_t)c * 8) = cvt8(v0, v1, sc);
  }
}

__global__ __launch_bounds__(256) void k_dq_dn(const float* __restrict__ w,
                                               const float* __restrict__ s,
                                               unsigned short* __restrict__ o) {
  const int N = NEXP * HDIM * FDIM / 8;
  for (int c = blockIdx.x * 256 + threadIdx.x; c < N; c += 8192 * 256) {
    int f8  = c & 127;
    int row = c >> 7;
    int e   = row >> 11;
    int h   = row & 2047;
    float sc = s[e * 128 + (h >> 7) * 8 + (f8 >> 4)];
    const floatx4 v0 = *(const floatx4*)(w + (size_t)c * 8);
    const floatx4 v1 = *(const floatx4*)(w + (size_t)c * 8 + 4);
    *(short8v*)(o + (size_t)c * 8) = cvt8(v0, v1, sc);
  }
}

// ---- GEMM1: act = silu(h@Wg^T)*(h@Wu^T); BM=256 x 32 act-cols ----
// grid (WMAX1, 32): wave w owns rows [w*64,w*64+64), all 32 cols. BK=64.
__global__ __launch_bounds__(256, 4) void k_gemm1n(
    const unsigned short* __restrict__ hb,
    const unsigned short* __restrict__ wgb,
    const int* __restrict__ wsI,
    unsigned short* __restrict__ act)
{
  if ((int)blockIdx.x >= wsI[25]) return;
  const int item = wsI[96 + blockIdx.x];
  const int e    = item >> 8;
  const int r0   = (item & 255) << 8;
  const int cnt  = wsI[e];
  const int off  = wsI[16 + e];
  const int c0   = blockIdx.y * 32;          // act col base
  const int* etok = wsI + ETOK_OFF;

  __shared__ unsigned short As[256][64];     // 32 KB
  __shared__ unsigned short Bs[64][64];      // 8 KB

  const int tid = threadIdx.x, lane = tid & 63, w = tid >> 6;
  const int kg = lane >> 4, l15 = lane & 15, lr = lane >> 3, lc = lane & 7;

  unsigned int aoff[8];
#pragma unroll
  for (int i = 0; i < 8; i++) {
    int ra  = w * 64 + i * 8 + lr;
    int swz = (lc ^ (ra & 7)) * 8;
    int ent = r0 + ra; if (ent >= cnt) ent = cnt - 1;
    aoff[i] = (unsigned)etok[off + ent] * 2048u + (unsigned)swz;
  }
  unsigned int boff[2];
#pragma unroll
  for (int i = 0; i < 2; i++) {
    int rb  = (w * 2 + i) * 8 + lr;          // [0,64): 32 gate + 32 up
    int swz = (lc ^ (rb & 7)) * 8;
    int gr  = (rb < 32) ? (c0 + rb) : (1024 + c0 + rb - 32);
    boff[i] = ((unsigned)e * 2048u + (unsigned)gr) * 2048u + (unsigned)swz;
  }

  floatx4 acc[4][4] = {};

  for (int k0 = 0; k0 < HDIM; k0 += 64) {
#pragma unroll
    for (int i = 0; i < 8; i++)
      gll16(hb + aoff[i] + k0, (char*)As + (w * 8 + i) * 1024);
#pragma unroll
    for (int i = 0; i < 2; i++)
      gll16(wgb + boff[i] + k0, (char*)Bs + (w * 2 + i) * 1024);
    __syncthreads();

    const char* Ab = (const char*)As;
    const char* Bb = (const char*)Bs;
#pragma unroll
    for (int ks = 0; ks < 2; ks++) {
      short8v a[4], b[4];
#pragma unroll
      for (int m = 0; m < 4; m++) {
        int r = w * 64 + m * 16 + l15;
        a[m] = *(const short8v*)(Ab + r * 128 + (((ks * 4 + kg) ^ (r & 7)) << 4));
      }
#pragma unroll
      for (int n = 0; n < 4; n++) {
        int rb = n * 16 + l15;
        b[n] = *(const short8v*)(Bb + rb * 128 + (((ks * 4 + kg) ^ (rb & 7)) << 4));
      }
#pragma unroll
      for (int m = 0; m < 4; m++)
#pragma unroll
        for (int n = 0; n < 4; n++)
          acc[m][n] = __builtin_amdgcn_mfma_f32_16x16x32_bf16(a[m], b[n], acc[m][n], 0, 0, 0);
    }
    __syncthreads();
  }

#pragma unroll
  for (int m = 0; m < 4; m++) {
    int rbase = r0 + w * 64 + m * 16 + kg * 4;
#pragma unroll
    for (int reg = 0; reg < 4; reg++) {
      int rr = rbase + reg;
      if (rr < cnt) {
#pragma unroll
        for (int n = 0; n < 2; n++) {
          float g = acc[m][n][reg];       // gate cols c0 + n*16 + l15
          float u = acc[m][n + 2][reg];   // matching up
          float a = g / (1.f + __expf(-g)) * u;
          act[(size_t)(off + rr) * FDIM + c0 + n * 16 + l15] = f2bf(a);
        }
      }
    }
  }
}

// ---- GEMM2: oe[entry] = w_entry * (act @ Wdn^T); BM=128 x 64 h-cols ----
// grid (WMAX2, 32). Plain stores (no atomics); k_reduce combines K=2 entries.
__global__ __launch_bounds__(256, 5) void k_gemm2n(
    const unsigned short* __restrict__ wdb,
    const int* __restrict__ wsI,
    const unsigned short* __restrict__ act,
    float* __restrict__ oe)
{
  if ((int)blockIdx.x >= wsI[24]) return;
  const int item = wsI[48 + blockIdx.x];
  const int e    = item >> 8;
  const int r0   = (item & 255) << 7;
  const int cnt  = wsI[e];
  const int off  = wsI[16 + e];
  const int c0   = blockIdx.y * 64;          // h col base
  const float* ew = (const float*)(wsI + ETOK_OFF + NENT);

  __shared__ unsigned short As[128][64];     // 16 KB
  __shared__ unsigned short Bs[64][64];      // 8 KB

  const int tid = threadIdx.x, lane = tid & 63, w = tid >> 6;
  const int kg = lane >> 4, l15 = lane & 15, lr = lane >> 3, lc = lane & 7;
  const int wr = (w >> 1) * 64, wc = w & 1;

  unsigned int aoff[4];
#pragma unroll
  for (int i = 0; i < 4; i++) {
    int ra  = (w * 4 + i) * 8 + lr;
    int swz = (lc ^ (ra & 7)) * 8;
    int ent = r0 + ra; if (ent >= cnt) ent = cnt - 1;
    aoff[i] = (unsigned)(off + ent) * 1024u + (unsigned)swz;
  }
  unsigned int boff[2];
#pragma unroll
  for (int i = 0; i < 2; i++) {
    int rb  = (w * 2 + i) * 8 + lr;
    int swz = (lc ^ (rb & 7)) * 8;
    boff[i] = ((unsigned)e * 2048u + (unsigned)(c0 + rb)) * 1024u + (unsigned)swz;
  }

  floatx4 acc[4][2] = {};

  for (int k0 = 0; k0 < FDIM; k0 += 64) {
#pragma unroll
    for (int i = 0; i < 4; i++)
      gll16(act + aoff[i] + k0, (char*)As + (w * 4 + i) * 1024);
#pragma unroll
    for (int i = 0; i < 2; i++)
      gll16(wdb + boff[i] + k0, (char*)Bs + (w * 2 + i) * 1024);
    __syncthreads();

    const char* Ab = (const char*)As;
    const char* Bb = (const char*)Bs;
#pragma unroll
    for (int ks = 0; ks < 2; ks++) {
      short8v a[4], b[2];
#pragma unroll
      for (int m = 0; m < 4; m++) {
        int r = wr + m * 16 + l15;
        a[m] = *(const short8v*)(Ab + r * 128 + (((ks * 4 + kg) ^ (r & 7)) << 4));
      }
#pragma unroll
      for (int n = 0; n < 2; n++) {
        int rb = wc * 32 + n * 16 + l15;
        b[n] = *(const short8v*)(Bb + rb * 128 + (((ks * 4 + kg) ^ (rb & 7)) << 4));
      }
#pragma unroll
      for (int m = 0; m < 4; m++)
#pragma unroll
        for (int n = 0; n < 2; n++)
          acc[m][n] = __builtin_amdgcn_mfma_f32_16x16x32_bf16(a[m], b[n], acc[m][n], 0, 0, 0);
    }
    __syncthreads();
  }

#pragma unroll
  for (int m = 0; m < 4; m++) {
    int rbase = r0 + wr + m * 16 + kg * 4;
#pragma unroll
    for (int reg = 0; reg < 4; reg++) {
      int rr = rbase + reg;
      if (rr < cnt) {
        float wgt = ew[off + rr];
#pragma unroll
        for (int n = 0; n < 2; n++)
          oe[(size_t)(off + rr) * HDIM + c0 + wc * 32 + n * 16 + l15] =
              wgt * acc[m][n][reg];
      }
    }
  }
}

__global__ __launch_bounds__(256) void k_reduce(const int* __restrict__ wsI,
                                                const float* __restrict__ oe,
                                                float* __restrict__ out) {
  int i4 = blockIdx.x * 256 + threadIdx.x;
  if (i4 >= T_TOK * HDIM / 4) return;
  int t  = i4 >> 9;
  int h4 = (i4 & 511) * 4;
  const int* inv = wsI + ETOK_OFF + 2 * NENT;
  int e0 = inv[2 * t], e1 = inv[2 * t + 1];
  floatx4 a = *(const floatx4*)&oe[(size_t)e0 * HDIM + h4];
  floatx4 b = *(const floatx4*)&oe[(size_t)e1 * HDIM + h4];
  floatx4 r = a + b;
  *(floatx4*)&out[(size_t)t * HDIM + h4] = r;
}

// ================= fallback (round-1 passing kernels) =================
__global__ __launch_bounds__(256) void k_gemm1_fb(
    const float* __restrict__ hidden, const float* __restrict__ wgu,
    const float* __restrict__ sgu, const int* __restrict__ wsI,
    unsigned short* __restrict__ act)
{
  const int e = blockIdx.y; const int cnt = wsI[e];
  const int r0 = blockIdx.x * 128; if (r0 >= cnt) return;
  const int off = wsI[16 + e]; const int c0 = blockIdx.z * 64;
  const int* etok = wsI + ETOK_OFF;
  __shared__ unsigned short As[128][40]; __shared__ unsigned short Bs[128][40];
  const int tid = threadIdx.x, lane = tid & 63, wv = tid >> 6;
  const int wr = (wv >> 1) * 64, wc = wv & 1, kg = lane >> 4, l15 = lane & 15;
  floatx4 acc[4][4] = {};
  for (int k0 = 0; k0 < HDIM; k0 += 32) {
#pragma unroll
    for (int c = tid; c < 1024; c += 256) {
      int row = c >> 3, k4 = c & 7;
      int rg = r0 + row; if (rg >= cnt) rg = cnt - 1;
      int tok = etok[off + rg];
      const floatx4 v = *(const floatx4*)&hidden[(size_t)tok * HDIM + k0 + k4 * 4];
      ushort4v o = { f2bf(v.x), f2bf(v.y), f2bf(v.z), f2bf(v.w) };
      *(ushort4v*)&As[row][k4 * 4] = o;
    }
#pragma unroll
    for (int c = tid; c < 1024; c += 256) {
      int row = c >> 3, k4 = c & 7;
      int gr = (row < 64) ? (c0 + row) : (FDIM + c0 + row - 64);
      float s = sgu[e * 256 + (gr >> 7) * 16 + (k0 >> 7)];
      const floatx4 v = *(const floatx4*)&wgu[((size_t)e * 2048 + gr) * HDIM + k0 + k4 * 4];
      ushort4v o = { f2bf(v.x * s), f2bf(v.y * s), f2bf(v.z * s), f2bf(v.w * s) };
      *(ushort4v*)&Bs[row][k4 * 4] = o;
    }
    __syncthreads();
    short8v a[4], b[4];
#pragma unroll
    for (int m = 0; m < 4; m++) a[m] = *(const short8v*)&As[wr + m * 16 + l15][kg * 8];
#pragma unroll
    for (int n = 0; n < 4; n++) {
      int br = (n < 2) ? (wc * 32 + n * 16) : (64 + wc * 32 + (n - 2) * 16);
      b[n] = *(const short8v*)&Bs[br + l15][kg * 8];
    }
#pragma unroll
    for (int m = 0; m < 4; m++)
#pragma unroll
      for (int n = 0; n < 4; n++)
        acc[m][n] = __builtin_amdgcn_mfma_f32_16x16x32_bf16(a[m], b[n], acc[m][n], 0, 0, 0);
    __syncthreads();
  }
#pragma unroll
  for (int m = 0; m < 4; m++) {
    int rbase = r0 + wr + m * 16 + kg * 4;
#pragma unroll
    for (int reg = 0; reg < 4; reg++) {
      int rr = rbase + reg;
      if (rr < cnt) {
#pragma unroll
        for (int n = 0; n < 2; n++) {
          float g = acc[m][n][reg], u = acc[m][n + 2][reg];
          float a = g / (1.f + expf(-g)) * u;
          act[(size_t)(off + rr) * FDIM + c0 + wc * 32 + n * 16 + l15] = f2bf(a);
        }
      }
    }
  }
}

__global__ __launch_bounds__(256) void k_gemm2_fb(
    const float* __restrict__ wdn, const float* __restrict__ sdn,
    const int* __restrict__ wsI, const unsigned short* __restrict__ act,
    float* __restrict__ out)
{
  const int e = blockIdx.y; const int cnt = wsI[e];
  const int r0 = blockIdx.x * 128; if (r0 >= cnt) return;
  const int off = wsI[16 + e]; const int c0 = blockIdx.z * 128;
  const int* etok = wsI + ETOK_OFF;
  const float* ew = (const float*)(wsI + ETOK_OFF + NENT);
  __shared__ unsigned short As[128][40]; __shared__ unsigned short Bs[128][40];
  const int tid = threadIdx.x, lane = tid & 63, wv = tid >> 6;
  const int wr = (wv >> 1) * 64, wc = wv & 1, kg = lane >> 4, l15 = lane & 15;
  floatx4 acc[4][4] = {};
  for (int k0 = 0; k0 < FDIM; k0 += 32) {
#pragma unroll
    for (int c = tid; c < 512; c += 256) {
      int row = c >> 2, k8 = c & 3;
      int rg = r0 + row; if (rg >= cnt) rg = cnt - 1;
      short8v v = *(const short8v*)&act[(size_t)(off + rg) * FDIM + k0 + k8 * 8];
      *(short8v*)&As[row][k8 * 8] = v;
    }
#pragma unroll
    for (int c = tid; c < 1024; c += 256) {
      int row = c >> 3, k4 = c & 7;
      int gr = c0 + row;
      float s = sdn[e * 128 + (gr >> 7) * 8 + (k0 >> 7)];
      const floatx4 v = *(const floatx4*)&wdn[((size_t)e * HDIM + gr) * FDIM + k0 + k4 * 4];
      ushort4v o = { f2bf(v.x * s), f2bf(v.y * s), f2bf(v.z * s), f2bf(v.w * s) };
      *(ushort4v*)&Bs[row][k4 * 4] = o;
    }
    __syncthreads();
    short8v a[4], b[4];
#pragma unroll
    for (int m = 0; m < 4; m++) a[m] = *(const short8v*)&As[wr + m * 16 + l15][kg * 8];
#pragma unroll
    for (int n = 0; n < 4; n++) b[n] = *(const short8v*)&Bs[wc * 64 + n * 16 + l15][kg * 8];
#pragma unroll
    for (int m = 0; m < 4; m++)
#pragma unroll
      for (int n = 0; n < 4; n++)
        acc[m][n] = __builtin_amdgcn_mfma_f32_16x16x32_bf16(a[m], b[n], acc[m][n], 0, 0, 0);
    __syncthreads();
  }
#pragma unroll
  for (int m = 0; m < 4; m++) {
    int rbase = r0 + wr + m * 16 + kg * 4;
#pragma unroll
    for (int reg = 0; reg < 4; reg++) {
      int rr = rbase + reg;
      if (rr < cnt) {
        int tok = etok[off + rr];
        float ww = ew[off + rr];
#pragma unroll
        for (int n = 0; n < 4; n++)
          atomicAdd(&out[(size_t)tok * HDIM + c0 + wc * 64 + n * 16 + l15], ww * acc[m][n][reg]);
      }
    }
  }
}

extern "C" void kernel_launch(void* const* d_in, const int* in_sizes, int n_in,
                              void* d_out, int out_size, void* d_ws, size_t ws_size,
                              hipStream_t stream) {
  const float* hidden = (const float*)d_in[0];
  const float* tw     = (const float*)d_in[1];
  const int*   ids    = (const int*)d_in[2];
  const float* wgu    = (const float*)d_in[3];
  const float* sgu    = (const float*)d_in[4];
  const float* wdn    = (const float*)d_in[5];
  const float* sdn    = (const float*)d_in[6];
  float* out = (float*)d_out;
  int* wsI = (int*)d_ws;

  const size_t NEED = 65536ull + (144ull << 20);
  if (ws_size >= NEED) {
    unsigned short* hb  = (unsigned short*)((char*)d_ws + 65536);
    unsigned short* wgb = hb  + (size_t)T_TOK * HDIM;
    unsigned short* wdb = wgb + (size_t)NEXP * 2 * FDIM * HDIM;
    unsigned short* act = wdb + (size_t)NEXP * HDIM * FDIM;
    float*          oe  = (float*)(act + (size_t)NENT * FDIM);

    k_init   <<<1, 128, 0, stream>>>(wsI);
    k_count  <<<16, 256, 0, stream>>>(ids, wsI);
    k_scan   <<<1, 1, 0, stream>>>(wsI);
    k_scatter<<<16, 256, 0, stream>>>(ids, tw, wsI);

    k_cast_h<<<T_TOK * HDIM / 8 / 256, 256, 0, stream>>>(hidden, hb);
    k_dq_gu <<<8192, 256, 0, stream>>>(wgu, sgu, wgb);
    k_dq_dn <<<8192, 256, 0, stream>>>(wdn, sdn, wdb);

    dim3 g1(WMAX1, 32);
    k_gemm1n<<<g1, 256, 0, stream>>>(hb, wgb, wsI, act);
    dim3 g2(WMAX2, 32);
    k_gemm2n<<<g2, 256, 0, stream>>>(wdb, wsI, act, oe);
    k_reduce<<<T_TOK * HDIM / 4 / 256, 256, 0, stream>>>(wsI, oe, out);
  } else {
    k_zero   <<<2048, 256, 0, stream>>>(out, wsI);
    k_count  <<<16, 256, 0, stream>>>(ids, wsI);
    k_scan   <<<1, 1, 0, stream>>>(wsI);
    k_scatter<<<16, 256, 0, stream>>>(ids, tw, wsI);
    unsigned short* act = (unsigned short*)((char*)d_ws + 65536);
    dim3 g1(NENT / 128, NEXP, FDIM / 64);
    k_gemm1_fb<<<g1, 256, 0, stream>>>(hidden, wgu, sgu, wsI, act);
    dim3 g2(NENT / 128, NEXP, HDIM / 128);
    k_gemm2_fb<<<g2, 256, 0, stream>>>(wdn, sdn, wsI, act, out);
  }
}

// Round 15
// 183.463 us; speedup vs baseline: 1.2244x; 1.1436x over previous
//
#include <hip/hip_runtime.h>
#include <hip/hip_bf16.h>

#define T_TOK 2048
#define HDIM  2048
#define FDIM  1024
#define NEXP  8
#define KSEL  2
#define NENT  (T_TOK*KSEL)   // 4096 routing entries
#define WMAX1 26             // gemm1 grid.x: nWork256<=24, so >=2 idle cols for dq_dn
#define WMAX2 40             // max 128-row work items

typedef __attribute__((ext_vector_type(8))) short   short8v;
typedef __attribute__((ext_vector_type(4))) float   floatx4;
typedef __attribute__((ext_vector_type(4))) unsigned short ushort4v;

__device__ __forceinline__ unsigned short f2bf(float f) {
  unsigned int u = __builtin_bit_cast(unsigned int, f);
  u += 0x7FFFu + ((u >> 16) & 1u);
  return (unsigned short)(u >> 16);
}

__device__ __forceinline__ short8v cvt8(floatx4 v0, floatx4 v1, float sc) {
  short8v r = { (short)f2bf(v0.x*sc), (short)f2bf(v0.y*sc),
                (short)f2bf(v0.z*sc), (short)f2bf(v0.w*sc),
                (short)f2bf(v1.x*sc), (short)f2bf(v1.y*sc),
                (short)f2bf(v1.z*sc), (short)f2bf(v1.w*sc) };
  return r;
}

__device__ __forceinline__ void gll16(const void* g, void* l) {
  __builtin_amdgcn_global_load_lds(
      (const __attribute__((address_space(1))) unsigned int*)g,
      (__attribute__((address_space(3))) unsigned int*)l, 16, 0, 0);
}

// ---- workspace layout ----
// wsI[0:8) cnt | wsI[16:24) offsets | wsI[24] nWork128 | wsI[25] nWork256
// wsI[48:88) wl128 | wsI[96:120) wl256
// wsI[128:+4096) entry token | (float*)[4096] entry weight | [4096] inv map
// byte 65536: hb (8Mi) | wgb (64Mi) | wdb (32Mi) | act (8Mi) | oe (32Mi)
#define ETOK_OFF 128

// single-launch routing: count -> scan -> scatter (1 block, 256 threads)
__global__ void k_route(const int* __restrict__ ids, const float* __restrict__ tw,
                        int* __restrict__ wsI) {
  __shared__ int cnt[8], off[8], cur[8];
  const int tid = threadIdx.x;
  if (tid < 8) { cnt[tid] = 0; cur[tid] = 0; }
  __syncthreads();
  for (int g = tid; g < NENT; g += 256)
    atomicAdd(&cnt[ids[g] & 7], 1);
  __syncthreads();
  if (tid == 0) {
    int s = 0, n1 = 0, n2 = 0;
    int* wl1 = wsI + 48;
    int* wl2 = wsI + 96;
    for (int e = 0; e < 8; e++) {
      off[e] = s; wsI[16 + e] = s; wsI[e] = cnt[e];
      int c = cnt[e]; s += c;
      int nb1 = (c + 127) >> 7;
      for (int rb = 0; rb < nb1; rb++) wl1[n1++] = (e << 8) | rb;
      int nb2 = (c + 255) >> 8;
      for (int rb = 0; rb < nb2; rb++) wl2[n2++] = (e << 8) | rb;
    }
    wsI[24] = n1; wsI[25] = n2;
  }
  __syncthreads();
  int*   etok = wsI + ETOK_OFF;
  float* ew   = (float*)(wsI + ETOK_OFF + NENT);
  int*   inv  = wsI + ETOK_OFF + 2 * NENT;
  for (int g = tid; g < NENT; g += 256) {
    int e = ids[g] & 7;
    int pos = atomicAdd(&cur[e], 1);
    int idx = off[e] + pos;
    etok[idx] = g >> 1;
    ew[idx]   = tw[g];
    inv[g]    = idx;
  }
}

// fallback-path zero (never hipMemsetAsync: rocclr fill kernel is slow)
__global__ __launch_bounds__(256) void k_zero(float* __restrict__ p) {
  const int N = T_TOK * HDIM / 4;
  for (int c = blockIdx.x * 256 + threadIdx.x; c < N; c += 2048 * 256) {
    floatx4 z = {0.f, 0.f, 0.f, 0.f};
    *(floatx4*)(p + (size_t)c * 4) = z;
  }
}

// ---- fused prep: cast hidden->bf16 AND dequant gate_up->bf16 (streaming) ----
__global__ __launch_bounds__(256) void k_prep(const float* __restrict__ h,
                                              unsigned short* __restrict__ hb,
                                              const float* __restrict__ w,
                                              const float* __restrict__ s,
                                              unsigned short* __restrict__ wgb) {
  const int gid = blockIdx.x * 256 + threadIdx.x;   // 8192*256 threads
  const int NH = T_TOK * HDIM / 8;                  // 524288
  if (gid < NH) {
    const floatx4 v0 = *(const floatx4*)(h + (size_t)gid * 8);
    const floatx4 v1 = *(const floatx4*)(h + (size_t)gid * 8 + 4);
    *(short8v*)(hb + (size_t)gid * 8) = cvt8(v0, v1, 1.f);
  }
  const int NG = NEXP * 2 * FDIM * HDIM / 8;        // 4194304
  for (int c = gid; c < NG; c += 8192 * 256) {
    int h8  = c & 255;
    int row = c >> 8;
    int e   = row >> 11;
    int orow = row & 2047;
    float sc = s[e * 256 + (orow >> 7) * 16 + (h8 >> 4)];
    const floatx4 v0 = *(const floatx4*)(w + (size_t)c * 8);
    const floatx4 v1 = *(const floatx4*)(w + (size_t)c * 8 + 4);
    *(short8v*)(wgb + (size_t)c * 8) = cvt8(v0, v1, sc);
  }
}

// ---- GEMM1: act = silu(h@Wg^T)*(h@Wu^T); BM=256 x 32 act-cols ----
// grid (WMAX1, 32). Blocks with x >= nWork256 dequant down_weight instead
// (their BW rides free under the latency-bound GEMM blocks).
__global__ __launch_bounds__(256, 4) void k_gemm1n(
    const unsigned short* __restrict__ hb,
    const unsigned short* __restrict__ wgb,
    const int* __restrict__ wsI,
    unsigned short* __restrict__ act,
    const float* __restrict__ wdn,
    const float* __restrict__ sdn,
    unsigned short* __restrict__ wdb)
{
  const int nW = wsI[25];
  if ((int)blockIdx.x >= nW) {
    // dq_dn worker
    const int nIdle = 32 * (WMAX1 - nW);
    const int wid   = (int)blockIdx.y * (WMAX1 - nW) + ((int)blockIdx.x - nW);
    const int N = NEXP * HDIM * FDIM / 8;           // 2097152
    for (int c = wid * 256 + threadIdx.x; c < N; c += nIdle * 256) {
      int f8  = c & 127;
      int row = c >> 7;
      int e   = row >> 11;
      int h   = row & 2047;
      float sc = sdn[e * 128 + (h >> 7) * 8 + (f8 >> 4)];
      const floatx4 v0 = *(const floatx4*)(wdn + (size_t)c * 8);
      const floatx4 v1 = *(const floatx4*)(wdn + (size_t)c * 8 + 4);
      *(short8v*)(wdb + (size_t)c * 8) = cvt8(v0, v1, sc);
    }
    return;
  }

  const int item = wsI[96 + blockIdx.x];
  const int e    = item >> 8;
  const int r0   = (item & 255) << 8;
  const int cnt  = wsI[e];
  const int off  = wsI[16 + e];
  const int c0   = blockIdx.y * 32;          // act col base
  const int* etok = wsI + ETOK_OFF;

  __shared__ unsigned short As[256][64];     // 32 KB
  __shared__ unsigned short Bs[64][64];      // 8 KB

  const int tid = threadIdx.x, lane = tid & 63, w = tid >> 6;
  const int kg = lane >> 4, l15 = lane & 15, lr = lane >> 3, lc = lane & 7;

  unsigned int aoff[8];
#pragma unroll
  for (int i = 0; i < 8; i++) {
    int ra  = w * 64 + i * 8 + lr;
    int swz = (lc ^ (ra & 7)) * 8;
    int ent = r0 + ra; if (ent >= cnt) ent = cnt - 1;
    aoff[i] = (unsigned)etok[off + ent] * 2048u + (unsigned)swz;
  }
  unsigned int boff[2];
#pragma unroll
  for (int i = 0; i < 2; i++) {
    int rb  = (w * 2 + i) * 8 + lr;          // [0,64): 32 gate + 32 up
    int swz = (lc ^ (rb & 7)) * 8;
    int gr  = (rb < 32) ? (c0 + rb) : (1024 + c0 + rb - 32);
    boff[i] = ((unsigned)e * 2048u + (unsigned)gr) * 2048u + (unsigned)swz;
  }

  floatx4 acc[4][4] = {};

  for (int k0 = 0; k0 < HDIM; k0 += 64) {
#pragma unroll
    for (int i = 0; i < 8; i++)
      gll16(hb + aoff[i] + k0, (char*)As + (w * 8 + i) * 1024);
#pragma unroll
    for (int i = 0; i < 2; i++)
      gll16(wgb + boff[i] + k0, (char*)Bs + (w * 2 + i) * 1024);
    __syncthreads();

    const char* Ab = (const char*)As;
    const char* Bb = (const char*)Bs;
#pragma unroll
    for (int ks = 0; ks < 2; ks++) {
      short8v a[4], b[4];
#pragma unroll
      for (int m = 0; m < 4; m++) {
        int r = w * 64 + m * 16 + l15;
        a[m] = *(const short8v*)(Ab + r * 128 + (((ks * 4 + kg) ^ (r & 7)) << 4));
      }
#pragma unroll
      for (int n = 0; n < 4; n++) {
        int rb = n * 16 + l15;
        b[n] = *(const short8v*)(Bb + rb * 128 + (((ks * 4 + kg) ^ (rb & 7)) << 4));
      }
#pragma unroll
      for (int m = 0; m < 4; m++)
#pragma unroll
        for (int n = 0; n < 4; n++)
          acc[m][n] = __builtin_amdgcn_mfma_f32_16x16x32_bf16(a[m], b[n], acc[m][n], 0, 0, 0);
    }
    __syncthreads();
  }

#pragma unroll
  for (int m = 0; m < 4; m++) {
    int rbase = r0 + w * 64 + m * 16 + kg * 4;
#pragma unroll
    for (int reg = 0; reg < 4; reg++) {
      int rr = rbase + reg;
      if (rr < cnt) {
#pragma unroll
        for (int n = 0; n < 2; n++) {
          float g = acc[m][n][reg];
          float u = acc[m][n + 2][reg];
          float a = g / (1.f + __expf(-g)) * u;
          act[(size_t)(off + rr) * FDIM + c0 + n * 16 + l15] = f2bf(a);
        }
      }
    }
  }
}

// ---- GEMM2: oe[entry] = w_entry * (act @ Wdn^T); BM=128 x 64 h-cols ----
__global__ __launch_bounds__(256, 5) void k_gemm2n(
    const unsigned short* __restrict__ wdb,
    const int* __restrict__ wsI,
    const unsigned short* __restrict__ act,
    float* __restrict__ oe)
{
  if ((int)blockIdx.x >= wsI[24]) return;
  const int item = wsI[48 + blockIdx.x];
  const int e    = item >> 8;
  const int r0   = (item & 255) << 7;
  const int cnt  = wsI[e];
  const int off  = wsI[16 + e];
  const int c0   = blockIdx.y * 64;
  const float* ew = (const float*)(wsI + ETOK_OFF + NENT);

  __shared__ unsigned short As[128][64];
  __shared__ unsigned short Bs[64][64];

  const int tid = threadIdx.x, lane = tid & 63, w = tid >> 6;
  const int kg = lane >> 4, l15 = lane & 15, lr = lane >> 3, lc = lane & 7;
  const int wr = (w >> 1) * 64, wc = w & 1;

  unsigned int aoff[4];
#pragma unroll
  for (int i = 0; i < 4; i++) {
    int ra  = (w * 4 + i) * 8 + lr;
    int swz = (lc ^ (ra & 7)) * 8;
    int ent = r0 + ra; if (ent >= cnt) ent = cnt - 1;
    aoff[i] = (unsigned)(off + ent) * 1024u + (unsigned)swz;
  }
  unsigned int boff[2];
#pragma unroll
  for (int i = 0; i < 2; i++) {
    int rb  = (w * 2 + i) * 8 + lr;
    int swz = (lc ^ (rb & 7)) * 8;
    boff[i] = ((unsigned)e * 2048u + (unsigned)(c0 + rb)) * 1024u + (unsigned)swz;
  }

  floatx4 acc[4][2] = {};

  for (int k0 = 0; k0 < FDIM; k0 += 64) {
#pragma unroll
    for (int i = 0; i < 4; i++)
      gll16(act + aoff[i] + k0, (char*)As + (w * 4 + i) * 1024);
#pragma unroll
    for (int i = 0; i < 2; i++)
      gll16(wdb + boff[i] + k0, (char*)Bs + (w * 2 + i) * 1024);
    __syncthreads();

    const char* Ab = (const char*)As;
    const char* Bb = (const char*)Bs;
#pragma unroll
    for (int ks = 0; ks < 2; ks++) {
      short8v a[4], b[2];
#pragma unroll
      for (int m = 0; m < 4; m++) {
        int r = wr + m * 16 + l15;
        a[m] = *(const short8v*)(Ab + r * 128 + (((ks * 4 + kg) ^ (r & 7)) << 4));
      }
#pragma unroll
      for (int n = 0; n < 2; n++) {
        int rb = wc * 32 + n * 16 + l15;
        b[n] = *(const short8v*)(Bb + rb * 128 + (((ks * 4 + kg) ^ (rb & 7)) << 4));
      }
#pragma unroll
      for (int m = 0; m < 4; m++)
#pragma unroll
        for (int n = 0; n < 2; n++)
          acc[m][n] = __builtin_amdgcn_mfma_f32_16x16x32_bf16(a[m], b[n], acc[m][n], 0, 0, 0);
    }
    __syncthreads();
  }

#pragma unroll
  for (int m = 0; m < 4; m++) {
    int rbase = r0 + wr + m * 16 + kg * 4;
#pragma unroll
    for (int reg = 0; reg < 4; reg++) {
      int rr = rbase + reg;
      if (rr < cnt) {
        float wgt = ew[off + rr];
#pragma unroll
        for (int n = 0; n < 2; n++)
          oe[(size_t)(off + rr) * HDIM + c0 + wc * 32 + n * 16 + l15] =
              wgt * acc[m][n][reg];
      }
    }
  }
}

__global__ __launch_bounds__(256) void k_reduce(const int* __restrict__ wsI,
                                                const float* __restrict__ oe,
                                                float* __restrict__ out) {
  int i4 = blockIdx.x * 256 + threadIdx.x;
  if (i4 >= T_TOK * HDIM / 4) return;
  int t  = i4 >> 9;
  int h4 = (i4 & 511) * 4;
  const int* inv = wsI + ETOK_OFF + 2 * NENT;
  int e0 = inv[2 * t], e1 = inv[2 * t + 1];
  floatx4 a = *(const floatx4*)&oe[(size_t)e0 * HDIM + h4];
  floatx4 b = *(const floatx4*)&oe[(size_t)e1 * HDIM + h4];
  floatx4 r = a + b;
  *(floatx4*)&out[(size_t)t * HDIM + h4] = r;
}

// ================= fallback (round-1 passing kernels) =================
__global__ __launch_bounds__(256) void k_gemm1_fb(
    const float* __restrict__ hidden, const float* __restrict__ wgu,
    const float* __restrict__ sgu, const int* __restrict__ wsI,
    unsigned short* __restrict__ act)
{
  const int e = blockIdx.y; const int cnt = wsI[e];
  const int r0 = blockIdx.x * 128; if (r0 >= cnt) return;
  const int off = wsI[16 + e]; const int c0 = blockIdx.z * 64;
  const int* etok = wsI + ETOK_OFF;
  __shared__ unsigned short As[128][40]; __shared__ unsigned short Bs[128][40];
  const int tid = threadIdx.x, lane = tid & 63, wv = tid >> 6;
  const int wr = (wv >> 1) * 64, wc = wv & 1, kg = lane >> 4, l15 = lane & 15;
  floatx4 acc[4][4] = {};
  for (int k0 = 0; k0 < HDIM; k0 += 32) {
#pragma unroll
    for (int c = tid; c < 1024; c += 256) {
      int row = c >> 3, k4 = c & 7;
      int rg = r0 + row; if (rg >= cnt) rg = cnt - 1;
      int tok = etok[off + rg];
      const floatx4 v = *(const floatx4*)&hidden[(size_t)tok * HDIM + k0 + k4 * 4];
      ushort4v o = { f2bf(v.x), f2bf(v.y), f2bf(v.z), f2bf(v.w) };
      *(ushort4v*)&As[row][k4 * 4] = o;
    }
#pragma unroll
    for (int c = tid; c < 1024; c += 256) {
      int row = c >> 3, k4 = c & 7;
      int gr = (row < 64) ? (c0 + row) : (FDIM + c0 + row - 64);
      float s = sgu[e * 256 + (gr >> 7) * 16 + (k0 >> 7)];
      const floatx4 v = *(const floatx4*)&wgu[((size_t)e * 2048 + gr) * HDIM + k0 + k4 * 4];
      ushort4v o = { f2bf(v.x * s), f2bf(v.y * s), f2bf(v.z * s), f2bf(v.w * s) };
      *(ushort4v*)&Bs[row][k4 * 4] = o;
    }
    __syncthreads();
    short8v a[4], b[4];
#pragma unroll
    for (int m = 0; m < 4; m++) a[m] = *(const short8v*)&As[wr + m * 16 + l15][kg * 8];
#pragma unroll
    for (int n = 0; n < 4; n++) {
      int br = (n < 2) ? (wc * 32 + n * 16) : (64 + wc * 32 + (n - 2) * 16);
      b[n] = *(const short8v*)&Bs[br + l15][kg * 8];
    }
#pragma unroll
    for (int m = 0; m < 4; m++)
#pragma unroll
      for (int n = 0; n < 4; n++)
        acc[m][n] = __builtin_amdgcn_mfma_f32_16x16x32_bf16(a[m], b[n], acc[m][n], 0, 0, 0);
    __syncthreads();
  }
#pragma unroll
  for (int m = 0; m < 4; m++) {
    int rbase = r0 + wr + m * 16 + kg * 4;
#pragma unroll
    for (int reg = 0; reg < 4; reg++) {
      int rr = rbase + reg;
      if (rr < cnt) {
#pragma unroll
        for (int n = 0; n < 2; n++) {
          float g = acc[m][n][reg], u = acc[m][n + 2][reg];
          float a = g / (1.f + expf(-g)) * u;
          act[(size_t)(off + rr) * FDIM + c0 + wc * 32 + n * 16 + l15] = f2bf(a);
        }
      }
    }
  }
}

__global__ __launch_bounds__(256) void k_gemm2_fb(
    const float* __restrict__ wdn, const float* __restrict__ sdn,
    const int* __restrict__ wsI, const unsigned short* __restrict__ act,
    float* __restrict__ out)
{
  const int e = blockIdx.y; const int cnt = wsI[e];
  const int r0 = blockIdx.x * 128; if (r0 >= cnt) return;
  const int off = wsI[16 + e]; const int c0 = blockIdx.z * 128;
  const int* etok = wsI + ETOK_OFF;
  const float* ew = (const float*)(wsI + ETOK_OFF + NENT);
  __shared__ unsigned short As[128][40]; __shared__ unsigned short Bs[128][40];
  const int tid = threadIdx.x, lane = tid & 63, wv = tid >> 6;
  const int wr = (wv >> 1) * 64, wc = wv & 1, kg = lane >> 4, l15 = lane & 15;
  floatx4 acc[4][4] = {};
  for (int k0 = 0; k0 < FDIM; k0 += 32) {
#pragma unroll
    for (int c = tid; c < 512; c += 256) {
      int row = c >> 2, k8 = c & 3;
      int rg = r0 + row; if (rg >= cnt) rg = cnt - 1;
      short8v v = *(const short8v*)&act[(size_t)(off + rg) * FDIM + k0 + k8 * 8];
      *(short8v*)&As[row][k8 * 8] = v;
    }
#pragma unroll
    for (int c = tid; c < 1024; c += 256) {
      int row = c >> 3, k4 = c & 7;
      int gr = c0 + row;
      float s = sdn[e * 128 + (gr >> 7) * 8 + (k0 >> 7)];
      const floatx4 v = *(const floatx4*)&wdn[((size_t)e * HDIM + gr) * FDIM + k0 + k4 * 4];
      ushort4v o = { f2bf(v.x * s), f2bf(v.y * s), f2bf(v.z * s), f2bf(v.w * s) };
      *(ushort4v*)&Bs[row][k4 * 4] = o;
    }
    __syncthreads();
    short8v a[4], b[4];
#pragma unroll
    for (int m = 0; m < 4; m++) a[m] = *(const short8v*)&As[wr + m * 16 + l15][kg * 8];
#pragma unroll
    for (int n = 0; n < 4; n++) b[n] = *(const short8v*)&Bs[wc * 64 + n * 16 + l15][kg * 8];
#pragma unroll
    for (int m = 0; m < 4; m++)
#pragma unroll
      for (int n = 0; n < 4; n++)
        acc[m][n] = __builtin_amdgcn_mfma_f32_16x16x32_bf16(a[m], b[n], acc[m][n], 0, 0, 0);
    __syncthreads();
  }
#pragma unroll
  for (int m = 0; m < 4; m++) {
    int rbase = r0 + wr + m * 16 + kg * 4;
#pragma unroll
    for (int reg = 0; reg < 4; reg++) {
      int rr = rbase + reg;
      if (rr < cnt) {
        int tok = etok[off + rr];
        float ww = ew[off + rr];
#pragma unroll
        for (int n = 0; n < 4; n++)
          atomicAdd(&out[(size_t)tok * HDIM + c0 + wc * 64 + n * 16 + l15], ww * acc[m][n][reg]);
      }
    }
  }
}

extern "C" void kernel_launch(void* const* d_in, const int* in_sizes, int n_in,
                              void* d_out, int out_size, void* d_ws, size_t ws_size,
                              hipStream_t stream) {
  const float* hidden = (const float*)d_in[0];
  const float* tw     = (const float*)d_in[1];
  const int*   ids    = (const int*)d_in[2];
  const float* wgu    = (const float*)d_in[3];
  const float* sgu    = (const float*)d_in[4];
  const float* wdn    = (const float*)d_in[5];
  const float* sdn    = (const float*)d_in[6];
  float* out = (float*)d_out;
  int* wsI = (int*)d_ws;

  const size_t NEED = 65536ull + (144ull << 20);
  if (ws_size >= NEED) {
    unsigned short* hb  = (unsigned short*)((char*)d_ws + 65536);
    unsigned short* wgb = hb  + (size_t)T_TOK * HDIM;
    unsigned short* wdb = wgb + (size_t)NEXP * 2 * FDIM * HDIM;
    unsigned short* act = wdb + (size_t)NEXP * HDIM * FDIM;
    float*          oe  = (float*)(act + (size_t)NENT * FDIM);

    k_route<<<1, 256, 0, stream>>>(ids, tw, wsI);
    k_prep <<<8192, 256, 0, stream>>>(hidden, hb, wgu, sgu, wgb);

    dim3 g1(WMAX1, 32);
    k_gemm1n<<<g1, 256, 0, stream>>>(hb, wgb, wsI, act, wdn, sdn, wdb);
    dim3 g2(WMAX2, 32);
    k_gemm2n<<<g2, 256, 0, stream>>>(wdb, wsI, act, oe);
    k_reduce<<<T_TOK * HDIM / 4 / 256, 256, 0, stream>>>(wsI, oe, out);
  } else {
    k_zero <<<2048, 256, 0, stream>>>(out);
    k_route<<<1, 256, 0, stream>>>(ids, tw, wsI);
    unsigned short* act = (unsigned short*)((char*)d_ws + 65536);
    dim3 g1(NENT / 128, NEXP, FDIM / 64);
    k_gemm1_fb<<<g1, 256, 0, stream>>>(hidden, wgu, sgu, wsI, act);
    dim3 g2(NENT / 128, NEXP, HDIM / 128);
    k_gemm2_fb<<<g2, 256, 0, stream>>>(wdn, sdn, wsI, act, out);
  }
}